// Round 1
// baseline (2405.907 us; speedup 1.0000x reference)
//
#include <hip/hip_runtime.h>

#define EPS 1e-5f
#define NTHR 256
#define NBLK 2048

// d_ws stats layout (floats):
//   [0:32)   sum(z1)    [32:64)  sum(z1^2)
//   [64:96)  sum(z2)    [96:128) sum(z2^2)
//   [128:160) sum(z3)   [160:192) sum(z3^2)

__device__ __forceinline__ void load_row16(const float* __restrict__ x, int row, float xv[16]) {
    const float4* xr = reinterpret_cast<const float4*>(x) + (size_t)row * 4;
    float4 q0 = xr[0], q1 = xr[1], q2 = xr[2], q3 = xr[3];
    xv[0]=q0.x; xv[1]=q0.y; xv[2]=q0.z; xv[3]=q0.w;
    xv[4]=q1.x; xv[5]=q1.y; xv[6]=q1.z; xv[7]=q1.w;
    xv[8]=q2.x; xv[9]=q2.y; xv[10]=q2.z; xv[11]=q2.w;
    xv[12]=q3.x; xv[13]=q3.y; xv[14]=q3.z; xv[15]=q3.w;
}

__device__ __forceinline__ void linear16(const float* __restrict__ W, const float* __restrict__ b,
                                         const float xv[16], float z[32]) {
    #pragma unroll
    for (int j = 0; j < 32; ++j) {
        float a = b[j];
        #pragma unroll
        for (int k = 0; k < 16; ++k) a = fmaf(W[j*16+k], xv[k], a);
        z[j] = a;
    }
}

__device__ __forceinline__ void linear32(const float* __restrict__ W, const float* __restrict__ b,
                                         const float p[32], float z[32]) {
    #pragma unroll
    for (int j = 0; j < 32; ++j) {
        float a = b[j];
        #pragma unroll
        for (int k = 0; k < 32; ++k) a = fmaf(W[j*32+k], p[k], a);
        z[j] = a;
    }
}

// BN(scale,shift)+ReLU in place; a_s/c_s are 32-entry LDS arrays
__device__ __forceinline__ void bnrelu(float z[32], const float* a_s, const float* c_s) {
    #pragma unroll
    for (int j = 0; j < 32; ++j) z[j] = fmaxf(fmaf(a_s[j], z[j], c_s[j]), 0.f);
}

// derive a = g*rsqrt(var+eps), c = be - mean*a from raw sums (threads 0..31)
__device__ __forceinline__ void derive_ac(const float* __restrict__ stats, int off,
                                          const float* __restrict__ g, const float* __restrict__ be,
                                          float invN, float* a_s, float* c_s) {
    if (threadIdx.x < 32) {
        float m = stats[off + threadIdx.x] * invN;
        float v = stats[off + 32 + threadIdx.x] * invN - m * m;
        float a = g[threadIdx.x] * rsqrtf(v + EPS);
        a_s[threadIdx.x] = a;
        c_s[threadIdx.x] = fmaf(-m, a, be[threadIdx.x]);
    }
}

// block-reduce 32 per-thread accumulators and atomically add to gdst[0..31]
// lds must hold 4*32 floats; blockDim.x == 256 assumed
__device__ __forceinline__ void reduce32_atomic(float (&acc)[32], float* __restrict__ gdst, float* lds) {
    int lane = threadIdx.x & 63;
    int wave = threadIdx.x >> 6;
    #pragma unroll
    for (int j = 0; j < 32; ++j) {
        float v = acc[j];
        v += __shfl_down(v, 32);
        v += __shfl_down(v, 16);
        v += __shfl_down(v, 8);
        v += __shfl_down(v, 4);
        v += __shfl_down(v, 2);
        v += __shfl_down(v, 1);
        if (lane == 0) lds[wave * 32 + j] = v;
    }
    __syncthreads();
    if (threadIdx.x < 32) {
        float v = lds[threadIdx.x] + lds[32 + threadIdx.x] + lds[64 + threadIdx.x] + lds[96 + threadIdx.x];
        atomicAdd(&gdst[threadIdx.x], v);
    }
}

__global__ __launch_bounds__(NTHR) void k_stats1(
    const float* __restrict__ x, const float* __restrict__ W1, const float* __restrict__ b1,
    float* __restrict__ stats, int N)
{
    __shared__ float lds[4 * 32];
    float sum[32], sq[32];
    #pragma unroll
    for (int j = 0; j < 32; ++j) { sum[j] = 0.f; sq[j] = 0.f; }
    for (int row = blockIdx.x * blockDim.x + threadIdx.x; row < N; row += gridDim.x * blockDim.x) {
        float xv[16], z[32];
        load_row16(x, row, xv);
        linear16(W1, b1, xv, z);
        #pragma unroll
        for (int j = 0; j < 32; ++j) { sum[j] += z[j]; sq[j] = fmaf(z[j], z[j], sq[j]); }
    }
    reduce32_atomic(sum, stats + 0, lds);
    __syncthreads();
    reduce32_atomic(sq, stats + 32, lds);
}

__global__ __launch_bounds__(NTHR) void k_stats2(
    const float* __restrict__ x,
    const float* __restrict__ W1, const float* __restrict__ b1,
    const float* __restrict__ g1, const float* __restrict__ be1,
    const float* __restrict__ W2, const float* __restrict__ b2,
    float* __restrict__ stats, int N)
{
    __shared__ float lds[4 * 32];
    __shared__ float a1[32], c1[32];
    float invN = 1.0f / (float)N;
    derive_ac(stats, 0, g1, be1, invN, a1, c1);
    __syncthreads();

    float sum[32], sq[32];
    #pragma unroll
    for (int j = 0; j < 32; ++j) { sum[j] = 0.f; sq[j] = 0.f; }
    for (int row = blockIdx.x * blockDim.x + threadIdx.x; row < N; row += gridDim.x * blockDim.x) {
        float xv[16], z1[32], z2[32];
        load_row16(x, row, xv);
        linear16(W1, b1, xv, z1);
        bnrelu(z1, a1, c1);
        linear32(W2, b2, z1, z2);
        #pragma unroll
        for (int j = 0; j < 32; ++j) { sum[j] += z2[j]; sq[j] = fmaf(z2[j], z2[j], sq[j]); }
    }
    reduce32_atomic(sum, stats + 64, lds);
    __syncthreads();
    reduce32_atomic(sq, stats + 96, lds);
}

__global__ __launch_bounds__(NTHR) void k_stats3(
    const float* __restrict__ x,
    const float* __restrict__ W1, const float* __restrict__ b1,
    const float* __restrict__ g1, const float* __restrict__ be1,
    const float* __restrict__ W2, const float* __restrict__ b2,
    const float* __restrict__ g2, const float* __restrict__ be2,
    const float* __restrict__ W3, const float* __restrict__ b3,
    float* __restrict__ stats, int N)
{
    __shared__ float lds[4 * 32];
    __shared__ float a1[32], c1[32], a2[32], c2[32];
    float invN = 1.0f / (float)N;
    derive_ac(stats, 0, g1, be1, invN, a1, c1);
    derive_ac(stats, 64, g2, be2, invN, a2, c2);
    __syncthreads();

    float sum[32], sq[32];
    #pragma unroll
    for (int j = 0; j < 32; ++j) { sum[j] = 0.f; sq[j] = 0.f; }
    for (int row = blockIdx.x * blockDim.x + threadIdx.x; row < N; row += gridDim.x * blockDim.x) {
        float xv[16], z1[32], z2[32];
        load_row16(x, row, xv);
        linear16(W1, b1, xv, z1);
        bnrelu(z1, a1, c1);
        linear32(W2, b2, z1, z2);
        bnrelu(z2, a2, c2);
        linear32(W3, b3, z2, z1);   // reuse z1 as z3
        #pragma unroll
        for (int j = 0; j < 32; ++j) { sum[j] += z1[j]; sq[j] = fmaf(z1[j], z1[j], sq[j]); }
    }
    reduce32_atomic(sum, stats + 128, lds);
    __syncthreads();
    reduce32_atomic(sq, stats + 160, lds);
}

__global__ __launch_bounds__(NTHR) void k_out(
    const float* __restrict__ x,
    const float* __restrict__ W1, const float* __restrict__ b1,
    const float* __restrict__ g1, const float* __restrict__ be1,
    const float* __restrict__ W2, const float* __restrict__ b2,
    const float* __restrict__ g2, const float* __restrict__ be2,
    const float* __restrict__ W3, const float* __restrict__ b3,
    const float* __restrict__ g3, const float* __restrict__ be3,
    const float* __restrict__ W4, const float* __restrict__ b4,
    const float* __restrict__ stats, float* __restrict__ out, int N)
{
    __shared__ float a1[32], c1[32], a2[32], c2[32], a3[32], c3[32];
    float invN = 1.0f / (float)N;
    derive_ac(stats, 0, g1, be1, invN, a1, c1);
    derive_ac(stats, 64, g2, be2, invN, a2, c2);
    derive_ac(stats, 128, g3, be3, invN, a3, c3);
    __syncthreads();

    for (int row = blockIdx.x * blockDim.x + threadIdx.x; row < N; row += gridDim.x * blockDim.x) {
        float xv[16], z1[32], z2[32];
        load_row16(x, row, xv);
        linear16(W1, b1, xv, z1);
        bnrelu(z1, a1, c1);
        linear32(W2, b2, z1, z2);
        bnrelu(z2, a2, c2);
        linear32(W3, b3, z2, z1);   // z3 in z1
        bnrelu(z1, a3, c3);
        float o = b4[0];
        #pragma unroll
        for (int k = 0; k < 32; ++k) o = fmaf(W4[k], z1[k], o);
        out[row] = o;
    }
}

extern "C" void kernel_launch(void* const* d_in, const int* in_sizes, int n_in,
                              void* d_out, int out_size, void* d_ws, size_t ws_size,
                              hipStream_t stream) {
    const float* x   = (const float*)d_in[0];
    const float* W1  = (const float*)d_in[1];
    const float* b1  = (const float*)d_in[2];
    const float* g1  = (const float*)d_in[3];
    const float* be1 = (const float*)d_in[4];
    const float* W2  = (const float*)d_in[5];
    const float* b2  = (const float*)d_in[6];
    const float* g2  = (const float*)d_in[7];
    const float* be2 = (const float*)d_in[8];
    const float* W3  = (const float*)d_in[9];
    const float* b3  = (const float*)d_in[10];
    const float* g3  = (const float*)d_in[11];
    const float* be3 = (const float*)d_in[12];
    const float* W4  = (const float*)d_in[13];
    const float* b4  = (const float*)d_in[14];
    float* out = (float*)d_out;
    float* stats = (float*)d_ws;
    int N = in_sizes[0] / 16;

    // stats region must be zeroed every call (harness re-poisons d_ws)
    hipMemsetAsync(stats, 0, 192 * sizeof(float), stream);

    k_stats1<<<NBLK, NTHR, 0, stream>>>(x, W1, b1, stats, N);
    k_stats2<<<NBLK, NTHR, 0, stream>>>(x, W1, b1, g1, be1, W2, b2, stats, N);
    k_stats3<<<NBLK, NTHR, 0, stream>>>(x, W1, b1, g1, be1, W2, b2, g2, be2, W3, b3, stats, N);
    k_out<<<NBLK, NTHR, 0, stream>>>(x, W1, b1, g1, be1, W2, b2, g2, be2, W3, b3, g3, be3,
                                     W4, b4, stats, out, N);
}

// Round 2
// 335.636 us; speedup vs baseline: 7.1682x; 7.1682x over previous
//
#include <hip/hip_runtime.h>

#define EPS 1e-5f
#define NTHR 256
#define NBLK 1024
#define NSLOT 8

typedef __bf16 bf16x8 __attribute__((ext_vector_type(8)));
typedef float f32x16 __attribute__((ext_vector_type(16)));

// ws layout: stats slots for layer L in [0,3): ws[L*NSLOT*64 + slot*64 + idx]
//   idx 0..31 = sum(z_L), idx 32..63 = sum(z_L^2)  (z includes linear bias)
//
// Layout algebra (m74/m101-verified 32x32x16 mappings):
//   C/D: col=lane&31 (data row), row p = (reg&3)+8*(reg>>2)+4h, h=lane>>5
//   A:   m=lane&31, k=8h+j ;  B: n=lane&31, k=8h+j
// Feeding acc regs 0..7 (khalf0) / 8..15 (khalf1) as the next B-frag means
// MFMA k-index K=16*kh+8h+j consumes physical feature phi(K)=(j&3)+8*(j>>2)+4h+16*kh,
// so the next layer's weights use columns permuted by phi (involution).
// BN fold: relu(a*(z-mu)+be) = a*relu(z' + e), e = b - mu + be/a ; a>0 folds into
// the NEXT layer's weight columns; e folds into the MFMA accumulator init.

template<int DEPTH>
__global__ __launch_bounds__(NTHR) void k_fwd(
    const float* __restrict__ x,
    const float* __restrict__ W1, const float* __restrict__ b1,
    const float* __restrict__ g1, const float* __restrict__ be1,
    const float* __restrict__ W2, const float* __restrict__ b2,
    const float* __restrict__ g2, const float* __restrict__ be2,
    const float* __restrict__ W3, const float* __restrict__ b3,
    const float* __restrict__ g3, const float* __restrict__ be3,
    const float* __restrict__ W4, const float* __restrict__ b4,
    float* __restrict__ ws, float* __restrict__ out, int N)
{
    constexpr bool STATS = (DEPTH < 4);
    __shared__ float s_stat[3][64];
    __shared__ float s_a[3][32];
    __shared__ float s_e[3][32];
    __shared__ float s_b[64];

    const int tid = threadIdx.x;
    const float invN = 1.0f / (float)N;

    // Phase A: combine slot partials for layers whose stats are known
    if (tid < 64) {
        for (int L = 0; L < DEPTH - 1; ++L) {
            float a = 0.f;
            #pragma unroll
            for (int s = 0; s < NSLOT; ++s) a += ws[L * (NSLOT * 64) + s * 64 + tid];
            s_stat[L][tid] = a;
        }
    }
    __syncthreads();
    // Phase B: derive BN scale a and additive fold e per feature
    if (tid < 32) {
        const float* gs[3]  = {g1, g2, g3};
        const float* bes[3] = {be1, be2, be3};
        const float* bs[3]  = {b1, b2, b3};
        for (int L = 0; L < DEPTH - 1; ++L) {
            float mu = s_stat[L][tid] * invN;
            float v  = s_stat[L][32 + tid] * invN - mu * mu;
            float a  = gs[L][tid] * rsqrtf(v + EPS);
            s_a[L][tid] = a;
            s_e[L][tid] = bs[L][tid] - mu + bes[L][tid] / a;
        }
    }
    if (STATS && tid < 64) s_b[tid] = 0.f;
    __syncthreads();

    // Phase C: per-thread fragments and constants
    const int lane = tid & 63;
    const int h = lane >> 5;
    const int ml = lane & 31;

    bf16x8 w1f;
    {
        const float* p = W1 + ml * 16 + h * 8;
        #pragma unroll
        for (int j = 0; j < 8; ++j) w1f[j] = (__bf16)p[j];
    }
    bf16x8 w2f0 = {}, w2f1 = {}, w3f0 = {}, w3f1 = {};
    if (DEPTH >= 2) {
        #pragma unroll
        for (int kh = 0; kh < 2; ++kh)
            #pragma unroll
            for (int j = 0; j < 8; ++j) {
                int pk = (j & 3) + 8 * (j >> 2) + 4 * h + 16 * kh;
                float v = W2[ml * 32 + pk] * s_a[0][pk];
                if (kh == 0) w2f0[j] = (__bf16)v; else w2f1[j] = (__bf16)v;
            }
    }
    if (DEPTH >= 3) {
        #pragma unroll
        for (int kh = 0; kh < 2; ++kh)
            #pragma unroll
            for (int j = 0; j < 8; ++j) {
                int pk = (j & 3) + 8 * (j >> 2) + 4 * h + 16 * kh;
                float v = W3[ml * 32 + pk] * s_a[1][pk];
                if (kh == 0) w3f0[j] = (__bf16)v; else w3f1[j] = (__bf16)v;
            }
    }

    f32x16 c1, c2 = {}, c3 = {};
    float w4c[16];
    #pragma unroll
    for (int i = 0; i < 16; ++i) {
        int p = (i & 3) + 8 * (i >> 2) + 4 * h;
        c1[i] = (DEPTH == 1) ? b1[p] : s_e[0][p];
        if (DEPTH >= 2) c2[i] = (DEPTH == 2) ? b2[p] : s_e[1][p];
        if (DEPTH >= 3) c3[i] = (DEPTH == 3) ? b3[p] : s_e[2][p];
        if (DEPTH == 4) w4c[i] = W4[p] * s_a[2][p]; else w4c[i] = 0.f;
    }
    float b4v = (DEPTH == 4) ? b4[0] : 0.f;

    const int ntiles = N >> 5;
    const int nwaves = gridDim.x * (NTHR / 64);
    const int gwave  = blockIdx.x * (NTHR / 64) + (tid >> 6);

    float sums[16], sqs[16];
    #pragma unroll
    for (int i = 0; i < 16; ++i) { sums[i] = 0.f; sqs[i] = 0.f; }

    for (int t = gwave; t < ntiles; t += nwaves) {
        int row = (t << 5) + ml;
        const float4* xp = (const float4*)(x + (size_t)row * 16 + h * 8);
        float4 u0 = xp[0], u1 = xp[1];
        bf16x8 xf;
        xf[0] = (__bf16)u0.x; xf[1] = (__bf16)u0.y; xf[2] = (__bf16)u0.z; xf[3] = (__bf16)u0.w;
        xf[4] = (__bf16)u1.x; xf[5] = (__bf16)u1.y; xf[6] = (__bf16)u1.z; xf[7] = (__bf16)u1.w;

        f32x16 a1 = __builtin_amdgcn_mfma_f32_32x32x16_bf16(w1f, xf, c1, 0, 0, 0);
        if (DEPTH == 1) {
            #pragma unroll
            for (int i = 0; i < 16; ++i) { sums[i] += a1[i]; sqs[i] = fmaf(a1[i], a1[i], sqs[i]); }
            continue;
        }
        bf16x8 qa, qb;
        #pragma unroll
        for (int j = 0; j < 8; ++j) {
            qa[j] = (__bf16)fmaxf(a1[j], 0.f);
            qb[j] = (__bf16)fmaxf(a1[8 + j], 0.f);
        }
        f32x16 a2 = __builtin_amdgcn_mfma_f32_32x32x16_bf16(w2f0, qa, c2, 0, 0, 0);
        a2 = __builtin_amdgcn_mfma_f32_32x32x16_bf16(w2f1, qb, a2, 0, 0, 0);
        if (DEPTH == 2) {
            #pragma unroll
            for (int i = 0; i < 16; ++i) { sums[i] += a2[i]; sqs[i] = fmaf(a2[i], a2[i], sqs[i]); }
            continue;
        }
        bf16x8 pa, pb;
        #pragma unroll
        for (int j = 0; j < 8; ++j) {
            pa[j] = (__bf16)fmaxf(a2[j], 0.f);
            pb[j] = (__bf16)fmaxf(a2[8 + j], 0.f);
        }
        f32x16 a3 = __builtin_amdgcn_mfma_f32_32x32x16_bf16(w3f0, pa, c3, 0, 0, 0);
        a3 = __builtin_amdgcn_mfma_f32_32x32x16_bf16(w3f1, pb, a3, 0, 0, 0);
        if (DEPTH == 3) {
            #pragma unroll
            for (int i = 0; i < 16; ++i) { sums[i] += a3[i]; sqs[i] = fmaf(a3[i], a3[i], sqs[i]); }
            continue;
        }
        float o = 0.f;
        #pragma unroll
        for (int i = 0; i < 16; ++i) o = fmaf(w4c[i], fmaxf(a3[i], 0.f), o);
        o += __shfl_xor(o, 32);
        if (h == 0) out[row] = o + b4v;
    }

    if (STATS) {
        #pragma unroll
        for (int i = 0; i < 16; ++i) {
            float s = sums[i], q = sqs[i];
            #pragma unroll
            for (int d = 1; d <= 16; d <<= 1) {
                s += __shfl_xor(s, d);
                q += __shfl_xor(q, d);
            }
            if (ml == 0) {
                int p = (i & 3) + 8 * (i >> 2) + 4 * h;
                atomicAdd(&s_b[p], s);
                atomicAdd(&s_b[32 + p], q);
            }
        }
        __syncthreads();
        if (tid < 64) {
            int L = DEPTH - 1;
            atomicAdd(&ws[L * (NSLOT * 64) + (blockIdx.x & (NSLOT - 1)) * 64 + tid], s_b[tid]);
        }
    }
}

extern "C" void kernel_launch(void* const* d_in, const int* in_sizes, int n_in,
                              void* d_out, int out_size, void* d_ws, size_t ws_size,
                              hipStream_t stream) {
    const float* x   = (const float*)d_in[0];
    const float* W1  = (const float*)d_in[1];
    const float* b1  = (const float*)d_in[2];
    const float* g1  = (const float*)d_in[3];
    const float* be1 = (const float*)d_in[4];
    const float* W2  = (const float*)d_in[5];
    const float* b2  = (const float*)d_in[6];
    const float* g2  = (const float*)d_in[7];
    const float* be2 = (const float*)d_in[8];
    const float* W3  = (const float*)d_in[9];
    const float* b3  = (const float*)d_in[10];
    const float* g3  = (const float*)d_in[11];
    const float* be3 = (const float*)d_in[12];
    const float* W4  = (const float*)d_in[13];
    const float* b4  = (const float*)d_in[14];
    float* out = (float*)d_out;
    float* ws  = (float*)d_ws;
    int N = in_sizes[0] / 16;

    hipMemsetAsync(ws, 0, 3 * NSLOT * 64 * sizeof(float), stream);

    k_fwd<1><<<NBLK, NTHR, 0, stream>>>(x, W1, b1, g1, be1, W2, b2, g2, be2, W3, b3, g3, be3, W4, b4, ws, out, N);
    k_fwd<2><<<NBLK, NTHR, 0, stream>>>(x, W1, b1, g1, be1, W2, b2, g2, be2, W3, b3, g3, be3, W4, b4, ws, out, N);
    k_fwd<3><<<NBLK, NTHR, 0, stream>>>(x, W1, b1, g1, be1, W2, b2, g2, be2, W3, b3, g3, be3, W4, b4, ws, out, N);
    k_fwd<4><<<NBLK, NTHR, 0, stream>>>(x, W1, b1, g1, be1, W2, b2, g2, be2, W3, b3, g3, be3, W4, b4, ws, out, N);
}

// Round 3
// 323.708 us; speedup vs baseline: 7.4323x; 1.0368x over previous
//
#include <hip/hip_runtime.h>

#define EPS 1e-5f
#define NTHR 256
#define NBLK 1024
#define NSLOT 8

typedef __bf16 bf16x8 __attribute__((ext_vector_type(8)));
typedef float f32x16 __attribute__((ext_vector_type(16)));

// d_ws layout:
//   [0, N*16*2)              bf16 copy of x, tile-major in MFMA B-frag order:
//                            xb[(t*64 + lane)*8 .. +8) = 8 bf16 for (tile t, lane)
//   [N*16*2, +3*NSLOT*64*4)  stats slots: layer L: stats[L*NSLOT*64 + slot*64 + idx]
//                            idx 0..31 = sum(z_L), 32..63 = sum(z_L^2)
//
// Layout algebra (m74/m101-verified 32x32x16 mappings):
//   C/D: col=lane&31 (data row), row p = (reg&3)+8*(reg>>2)+4h, h=lane>>5
//   A:   m=lane&31, k=8h+j ;  B: n=lane&31, k=8h+j
// Acc regs 0..7 / 8..15 feed the next layer's B-frag; next weights use columns
// permuted by phi(K)=(j&3)+8*(j>>2)+4h+16*kh (involution). BN scale a>0 folds
// into next-layer weight columns; shift e folds into the MFMA accumulator init.

template<int DEPTH>
__global__ __launch_bounds__(NTHR) void k_fwd(
    const float* __restrict__ x, __bf16* __restrict__ xb,
    const float* __restrict__ W1, const float* __restrict__ b1,
    const float* __restrict__ g1, const float* __restrict__ be1,
    const float* __restrict__ W2, const float* __restrict__ b2,
    const float* __restrict__ g2, const float* __restrict__ be2,
    const float* __restrict__ W3, const float* __restrict__ b3,
    const float* __restrict__ g3, const float* __restrict__ be3,
    const float* __restrict__ W4, const float* __restrict__ b4,
    float* __restrict__ stats, float* __restrict__ out, int N)
{
    constexpr bool STATS = (DEPTH < 4);
    __shared__ float s_stat[3][64];
    __shared__ float s_a[3][32];
    __shared__ float s_e[3][32];
    __shared__ float s_b[64];

    const int tid = threadIdx.x;
    const float invN = 1.0f / (float)N;

    // Phase A: combine slot partials for layers whose stats are known
    if (tid < 64) {
        for (int L = 0; L < DEPTH - 1; ++L) {
            float a = 0.f;
            #pragma unroll
            for (int s = 0; s < NSLOT; ++s) a += stats[L * (NSLOT * 64) + s * 64 + tid];
            s_stat[L][tid] = a;
        }
    }
    __syncthreads();
    // Phase B: derive BN scale a and additive fold e per feature
    if (tid < 32) {
        const float* gs[3]  = {g1, g2, g3};
        const float* bes[3] = {be1, be2, be3};
        const float* bs[3]  = {b1, b2, b3};
        for (int L = 0; L < DEPTH - 1; ++L) {
            float mu = s_stat[L][tid] * invN;
            float v  = s_stat[L][32 + tid] * invN - mu * mu;
            float a  = gs[L][tid] * rsqrtf(v + EPS);
            s_a[L][tid] = a;
            s_e[L][tid] = bs[L][tid] - mu + bes[L][tid] / a;
        }
    }
    if (STATS && tid < 64) s_b[tid] = 0.f;
    __syncthreads();

    // Phase C: per-thread fragments and constants
    const int lane = tid & 63;
    const int h = lane >> 5;
    const int ml = lane & 31;

    bf16x8 w1f;
    {
        const float* p = W1 + ml * 16 + h * 8;
        #pragma unroll
        for (int j = 0; j < 8; ++j) w1f[j] = (__bf16)p[j];
    }
    bf16x8 w2f0 = {}, w2f1 = {}, w3f0 = {}, w3f1 = {};
    if (DEPTH >= 2) {
        #pragma unroll
        for (int kh = 0; kh < 2; ++kh)
            #pragma unroll
            for (int j = 0; j < 8; ++j) {
                int pk = (j & 3) + 8 * (j >> 2) + 4 * h + 16 * kh;
                float v = W2[ml * 32 + pk] * s_a[0][pk];
                if (kh == 0) w2f0[j] = (__bf16)v; else w2f1[j] = (__bf16)v;
            }
    }
    if (DEPTH >= 3) {
        #pragma unroll
        for (int kh = 0; kh < 2; ++kh)
            #pragma unroll
            for (int j = 0; j < 8; ++j) {
                int pk = (j & 3) + 8 * (j >> 2) + 4 * h + 16 * kh;
                float v = W3[ml * 32 + pk] * s_a[1][pk];
                if (kh == 0) w3f0[j] = (__bf16)v; else w3f1[j] = (__bf16)v;
            }
    }

    f32x16 c1, c2 = {}, c3 = {};
    float w4c[16];
    #pragma unroll
    for (int i = 0; i < 16; ++i) {
        int p = (i & 3) + 8 * (i >> 2) + 4 * h;
        c1[i] = (DEPTH == 1) ? b1[p] : s_e[0][p];
        if (DEPTH >= 2) c2[i] = (DEPTH == 2) ? b2[p] : s_e[1][p];
        if (DEPTH >= 3) c3[i] = (DEPTH == 3) ? b3[p] : s_e[2][p];
        if (DEPTH == 4) w4c[i] = W4[p] * s_a[2][p]; else w4c[i] = 0.f;
    }
    const float b4v = (DEPTH == 4) ? b4[0] : 0.f;

    const int ntiles = N >> 5;
    const int nwaves = gridDim.x * (NTHR / 64);
    const int gwave  = blockIdx.x * (NTHR / 64) + (tid >> 6);

    float sums[16], sqs[16];
    #pragma unroll
    for (int i = 0; i < 16; ++i) { sums[i] = 0.f; sqs[i] = 0.f; }

    // load (and for DEPTH==1: convert + stage) one tile's B-fragment
    auto loadx = [&](int t) -> bf16x8 {
        if (DEPTH == 1) {
            int row = (t << 5) + ml;
            const float4* xp = (const float4*)(x + (size_t)row * 16 + h * 8);
            float4 u0 = xp[0], u1 = xp[1];
            bf16x8 xf;
            xf[0] = (__bf16)u0.x; xf[1] = (__bf16)u0.y; xf[2] = (__bf16)u0.z; xf[3] = (__bf16)u0.w;
            xf[4] = (__bf16)u1.x; xf[5] = (__bf16)u1.y; xf[6] = (__bf16)u1.z; xf[7] = (__bf16)u1.w;
            *(bf16x8*)(xb + ((size_t)t * 64 + lane) * 8) = xf;
            return xf;
        } else {
            return *(const bf16x8*)(xb + ((size_t)t * 64 + lane) * 8);
        }
    };

    auto tile = [&](int t, bf16x8 xf) {
        f32x16 a1 = __builtin_amdgcn_mfma_f32_32x32x16_bf16(w1f, xf, c1, 0, 0, 0);
        if (DEPTH == 1) {
            #pragma unroll
            for (int i = 0; i < 16; ++i) { sums[i] += a1[i]; sqs[i] = fmaf(a1[i], a1[i], sqs[i]); }
            return;
        }
        bf16x8 qa, qb;
        #pragma unroll
        for (int j = 0; j < 8; ++j) {
            qa[j] = (__bf16)fmaxf(a1[j], 0.f);
            qb[j] = (__bf16)fmaxf(a1[8 + j], 0.f);
        }
        f32x16 a2 = __builtin_amdgcn_mfma_f32_32x32x16_bf16(w2f0, qa, c2, 0, 0, 0);
        a2 = __builtin_amdgcn_mfma_f32_32x32x16_bf16(w2f1, qb, a2, 0, 0, 0);
        if (DEPTH == 2) {
            #pragma unroll
            for (int i = 0; i < 16; ++i) { sums[i] += a2[i]; sqs[i] = fmaf(a2[i], a2[i], sqs[i]); }
            return;
        }
        bf16x8 pa, pb;
        #pragma unroll
        for (int j = 0; j < 8; ++j) {
            pa[j] = (__bf16)fmaxf(a2[j], 0.f);
            pb[j] = (__bf16)fmaxf(a2[8 + j], 0.f);
        }
        f32x16 a3 = __builtin_amdgcn_mfma_f32_32x32x16_bf16(w3f0, pa, c3, 0, 0, 0);
        a3 = __builtin_amdgcn_mfma_f32_32x32x16_bf16(w3f1, pb, a3, 0, 0, 0);
        if (DEPTH == 3) {
            #pragma unroll
            for (int i = 0; i < 16; ++i) { sums[i] += a3[i]; sqs[i] = fmaf(a3[i], a3[i], sqs[i]); }
            return;
        }
        float o = 0.f;
        #pragma unroll
        for (int i = 0; i < 16; ++i) o = fmaf(w4c[i], fmaxf(a3[i], 0.f), o);
        o += __shfl_xor(o, 32);
        if (h == 0) out[(t << 5) + ml] = o + b4v;
    };

    // 2-way unrolled grid-stride loop: both loads issued before either chain
    int t = gwave;
    for (; t + nwaves < ntiles; t += 2 * nwaves) {
        bf16x8 x0 = loadx(t);
        bf16x8 x1 = loadx(t + nwaves);
        tile(t, x0);
        tile(t + nwaves, x1);
    }
    if (t < ntiles) {
        bf16x8 x0 = loadx(t);
        tile(t, x0);
    }

    if (STATS) {
        #pragma unroll
        for (int i = 0; i < 16; ++i) {
            float s = sums[i], q = sqs[i];
            #pragma unroll
            for (int d = 1; d <= 16; d <<= 1) {
                s += __shfl_xor(s, d);
                q += __shfl_xor(q, d);
            }
            if (ml == 0) {
                int p = (i & 3) + 8 * (i >> 2) + 4 * h;
                atomicAdd(&s_b[p], s);
                atomicAdd(&s_b[32 + p], q);
            }
        }
        __syncthreads();
        if (tid < 64) {
            int L = DEPTH - 1;
            atomicAdd(&stats[L * (NSLOT * 64) + (blockIdx.x & (NSLOT - 1)) * 64 + tid], s_b[tid]);
        }
    }
}

extern "C" void kernel_launch(void* const* d_in, const int* in_sizes, int n_in,
                              void* d_out, int out_size, void* d_ws, size_t ws_size,
                              hipStream_t stream) {
    const float* x   = (const float*)d_in[0];
    const float* W1  = (const float*)d_in[1];
    const float* b1  = (const float*)d_in[2];
    const float* g1  = (const float*)d_in[3];
    const float* be1 = (const float*)d_in[4];
    const float* W2  = (const float*)d_in[5];
    const float* b2  = (const float*)d_in[6];
    const float* g2  = (const float*)d_in[7];
    const float* be2 = (const float*)d_in[8];
    const float* W3  = (const float*)d_in[9];
    const float* b3  = (const float*)d_in[10];
    const float* g3  = (const float*)d_in[11];
    const float* be3 = (const float*)d_in[12];
    const float* W4  = (const float*)d_in[13];
    const float* b4  = (const float*)d_in[14];
    float* out = (float*)d_out;
    int N = in_sizes[0] / 16;

    __bf16* xb   = (__bf16*)d_ws;
    float* stats = (float*)((char*)d_ws + (size_t)N * 16 * 2);

    hipMemsetAsync(stats, 0, 3 * NSLOT * 64 * sizeof(float), stream);

    k_fwd<1><<<NBLK, NTHR, 0, stream>>>(x, xb, W1, b1, g1, be1, W2, b2, g2, be2, W3, b3, g3, be3, W4, b4, stats, out, N);
    k_fwd<2><<<NBLK, NTHR, 0, stream>>>(x, xb, W1, b1, g1, be1, W2, b2, g2, be2, W3, b3, g3, be3, W4, b4, stats, out, N);
    k_fwd<3><<<NBLK, NTHR, 0, stream>>>(x, xb, W1, b1, g1, be1, W2, b2, g2, be2, W3, b3, g3, be3, W4, b4, stats, out, N);
    k_fwd<4><<<NBLK, NTHR, 0, stream>>>(x, xb, W1, b1, g1, be1, W2, b2, g2, be2, W3, b3, g3, be3, W4, b4, stats, out, N);
}